// Round 24
// baseline (203.518 us; speedup 1.0000x reference)
//
#include <hip/hip_runtime.h>

#define Bq 128
#define Sq 512
#define Cq 37
#define Dq 768
#define VST 40

typedef __attribute__((ext_vector_type(2))) float f32x2;
typedef __attribute__((ext_vector_type(4))) float f32x4;
typedef __attribute__((ext_vector_type(8))) short bf16x8;

static __device__ __forceinline__ f32x2 pk_fma(f32x2 a, f32x2 b, f32x2 c) {
  f32x2 d; asm("v_pk_fma_f32 %0, %1, %2, %3" : "=v"(d) : "v"(a), "v"(b), "v"(c));
  return d;
}
static __device__ __forceinline__ f32x2 pk_add(f32x2 a, f32x2 b) {
  f32x2 d; asm("v_pk_add_f32 %0, %1, %2" : "=v"(d) : "v"(a), "v"(b));
  return d;
}
static __device__ __forceinline__ float bcast(float v, int p) {
  return __int_as_float(__builtin_amdgcn_ds_bpermute(p << 2, __float_as_int(v)));
}

#define REP18(X) X(0)X(1)X(2)X(3)X(4)X(5)X(6)X(7)X(8)X(9)X(10)X(11)X(12)X(13) \
  X(14)X(15)X(16)X(17)
#define REP37(X) X(0)X(1)X(2)X(3)X(4)X(5)X(6)X(7)X(8)X(9)X(10)X(11)X(12)X(13) \
  X(14)X(15)X(16)X(17)X(18)X(19)X(20)X(21)X(22)X(23)X(24)X(25)X(26)X(27)X(28) \
  X(29)X(30)X(31)X(32)X(33)X(34)X(35)X(36)

#define BR(i) ((((i) & 3) == 0) ? gv[(i) >> 2].x : (((i) & 3) == 1) ? gv[(i) >> 2].y \
             : (((i) & 3) == 2) ? gv[(i) >> 2].z : gv[(i) >> 2].w)

// ---------------- Kernel 0: pre-split W into bf16 hi/lo B-fragments ----------------
__global__ __launch_bounds__(256) void prep_kernel(
    const float* __restrict__ W, unsigned short* __restrict__ Wbh,
    unsigned short* __restrict__ Wbl)
{
  int i = blockIdx.x * 256 + threadIdx.x;
  if (i >= 24 * 3 * 64 * 8) return;
  int ks = i / 1536, rem = i % 1536;
  int nt = rem / 512, rem2 = rem % 512;
  int lane = rem2 >> 3, j = rem2 & 7;
  int k = ks * 32 + (lane >> 4) * 8 + j;
  int c = nt * 16 + (lane & 15);
  float w = (c < Cq) ? W[(size_t)k * Cq + c] : 0.f;
  unsigned u = __float_as_uint(w);
  unsigned short h = (unsigned short)(u >> 16);
  float hr = __uint_as_float((unsigned)h << 16);
  float r = w - hr;
  Wbh[i] = h;
  Wbl[i] = (unsigned short)(__float_as_uint(r) >> 16);
}

// ---------------- Kernel 1: emissions via MFMA (R14, unchanged) ----------------
__global__ __launch_bounds__(256) void emis_kernel(
    const float* __restrict__ x, const unsigned short* __restrict__ Wbh,
    const unsigned short* __restrict__ Wbl, const float* __restrict__ bias,
    float* __restrict__ em)
{
  int tid = threadIdx.x, lane = tid & 63;
  int wv = tid >> 6;
  int tokBase = blockIdx.x * 64 + wv * 16;
  int row = lane & 15, kg = lane >> 4;
  const float* xr = x + (size_t)(tokBase + row) * Dq + kg * 8;
  const bf16x8* Bh = (const bf16x8*)Wbh;
  const bf16x8* Bl = (const bf16x8*)Wbl;
  f32x4 acc0 = {0.f, 0.f, 0.f, 0.f};
  f32x4 acc1 = {0.f, 0.f, 0.f, 0.f};
  f32x4 acc2 = {0.f, 0.f, 0.f, 0.f};

  float4 c0 = *(const float4*)(xr);
  float4 c1 = *(const float4*)(xr + 4);
  for (int ks = 0; ks < 24; ++ks) {
    float4 n0, n1;
    if (ks < 23) {
      n0 = *(const float4*)(xr + (ks + 1) * 32);
      n1 = *(const float4*)(xr + (ks + 1) * 32 + 4);
    }
    bf16x8 ah, al;
#define SPLIT(J, V) { unsigned u = __float_as_uint(V); \
    unsigned short h = (unsigned short)(u >> 16); \
    float hr = __uint_as_float((unsigned)h << 16); \
    float rr = (V) - hr; \
    ah[J] = (short)h; al[J] = (short)(__float_as_uint(rr) >> 16); }
    SPLIT(0, c0.x) SPLIT(1, c0.y) SPLIT(2, c0.z) SPLIT(3, c0.w)
    SPLIT(4, c1.x) SPLIT(5, c1.y) SPLIT(6, c1.z) SPLIT(7, c1.w)
#undef SPLIT
    int fi = (ks * 3) * 64 + lane;
    bf16x8 bh0 = Bh[fi], bh1 = Bh[fi + 64], bh2 = Bh[fi + 128];
    bf16x8 bl0 = Bl[fi], bl1 = Bl[fi + 64], bl2 = Bl[fi + 128];
    acc0 = __builtin_amdgcn_mfma_f32_16x16x32_bf16(al, bh0, acc0, 0, 0, 0);
    acc1 = __builtin_amdgcn_mfma_f32_16x16x32_bf16(al, bh1, acc1, 0, 0, 0);
    acc2 = __builtin_amdgcn_mfma_f32_16x16x32_bf16(al, bh2, acc2, 0, 0, 0);
    acc0 = __builtin_amdgcn_mfma_f32_16x16x32_bf16(ah, bl0, acc0, 0, 0, 0);
    acc1 = __builtin_amdgcn_mfma_f32_16x16x32_bf16(ah, bl1, acc1, 0, 0, 0);
    acc2 = __builtin_amdgcn_mfma_f32_16x16x32_bf16(ah, bl2, acc2, 0, 0, 0);
    acc0 = __builtin_amdgcn_mfma_f32_16x16x32_bf16(ah, bh0, acc0, 0, 0, 0);
    acc1 = __builtin_amdgcn_mfma_f32_16x16x32_bf16(ah, bh1, acc1, 0, 0, 0);
    acc2 = __builtin_amdgcn_mfma_f32_16x16x32_bf16(ah, bh2, acc2, 0, 0, 0);
    c0 = n0; c1 = n1;
  }
  int colc = lane & 15;
#pragma unroll
  for (int r = 0; r < 4; ++r) {
    size_t tok = (size_t)tokBase + kg * 4 + r;
    em[tok * Cq + colc]      = acc0[r] + bias[colc];
    em[tok * Cq + 16 + colc] = acc1[r] + bias[16 + colc];
    if (colc < 5)
      em[tok * Cq + 32 + colc] = acc2[r] + bias[32 + colc];
  }
}

// ---------------- Kernel 2: MEGA CRF (phases 1-2; bp bytes -> GLOBAL) ----------------
__global__ __launch_bounds__(320) void crf_mega_kernel(
    const float* __restrict__ em, const float* __restrict__ startv,
    const float* __restrict__ endv, const float* __restrict__ trans,
    const int* __restrict__ labels, const unsigned char* __restrict__ maskb,
    float* __restrict__ llp, unsigned char* __restrict__ bp,
    int* __restrict__ lenp, int* __restrict__ lastp, int* __restrict__ midp)
{
  __shared__ float semm[(Sq + 4) * Cq];
  __shared__ float vh[Sq * 40];
  __shared__ __align__(16) float sxA[64];
  __shared__ __align__(16) float sxB[64];
  __shared__ __align__(16) float sxC[64];
  __shared__ __align__(16) float sxD[64];
  __shared__ float mrgA[64], mrgB[64], mrgV[64], mrgU[64];
  __shared__ float s_score;
  int b = blockIdx.x;
  int tid = threadIdx.x, wid = tid >> 6, lane = tid & 63;
  int cl = lane < Cq ? lane : Cq - 1;

  int esz4 = (maskb[1] == 0) ? 1 : 0;
  int len = 0;
#pragma unroll
  for (int k = 0; k < 8; ++k) {
    size_t t = (size_t)lane + (size_t)k * 64;
    unsigned char mb = esz4 ? maskb[((size_t)b * Sq + t) * 4] : maskb[(size_t)b * Sq + t];
    len += (mb != 0);
  }
#pragma unroll
  for (int off = 32; off; off >>= 1) len += __shfl_xor(len, off);
  int m = len >> 1;

  const float4* src4 = (const float4*)(em + (size_t)b * Sq * Cq);
  float4* dst4 = (float4*)semm;
  for (int i = tid; i < (Sq * Cq) / 4; i += 320) dst4[i] = src4[i];
  if (tid < 4 * Cq) semm[Sq * Cq + tid] = 0.f;
  __syncthreads();

  const float L2E = 1.4426950408889634f, LN2 = 0.6931471805599453f;

  if (wid == 0) {
    // ---- alpha forward, exp domain, t = 1..m ----
    f32x2 E2[18];
#pragma unroll
    for (int i = 0; i < 18; ++i) {
      E2[i][0] = exp2f(trans[(2 * i) * Cq + cl] * L2E);
      E2[i][1] = exp2f(trans[(2 * i + 1) * Cq + cl] * L2E);
    }
    float E36 = exp2f(trans[36 * Cq + cl] * L2E);
    const float4* se4 = (const float4*)sxA;
    float a0 = (lane < Cq) ? (startv[cl] + semm[cl]) : -3.0e38f;
    float K0 = bcast(a0, 0);
    float ez = (lane < Cq) ? exp2f((a0 - K0) * L2E) : 0.f;
    int eacc = 0;
    float wA = exp2f(semm[1 * Cq + cl] * L2E), wB = exp2f(semm[2 * Cq + cl] * L2E);
    float wC = exp2f(semm[3 * Cq + cl] * L2E), wD = exp2f(semm[4 * Cq + cl] * L2E);
    for (int t = 1; t <= m; ++t) {
      sxA[lane] = ez;
      int tn = (t + 4 <= m) ? t + 4 : m;
      float raw = semm[tn * Cq + cl];
      float4 gv[10];
#pragma unroll
      for (int q = 0; q < 10; ++q) gv[q] = se4[q];
      int e0 = ((__float_as_int(gv[0].x) >> 23) & 255) - 127;
      float scale = __int_as_float((127 - e0) << 23);
      f32x2 sa = {0.f, 0.f}, sb2 = {0.f, 0.f};
#define FPK(i) { f32x2 g; \
      g[0] = ((i) & 1) ? gv[(i) >> 1].z : gv[(i) >> 1].x; \
      g[1] = ((i) & 1) ? gv[(i) >> 1].w : gv[(i) >> 1].y; \
      if ((i) & 1) sb2 = pk_fma(g, E2[i], sb2); else sa = pk_fma(g, E2[i], sa); }
      REP18(FPK)
#undef FPK
      float dot = ((sa[0] + sb2[0]) + (sa[1] + sb2[1])) + gv[9].x * E36;
      float wcur = wA; wA = wB; wB = wC; wC = wD;
      ez = dot * (wcur * scale);
      eacc += e0;
      wD = exp2f(raw * L2E);
    }
    mrgA[lane] = (lane < Cq) ? LN2 * (log2f(ez) + (float)eacc) + K0 : -3.0e38f;
  } else if (wid == 1) {
    // ---- beta backward, exp domain, t = len-2..m (row-dot) ----
    f32x2 E2[18];
#pragma unroll
    for (int i = 0; i < 18; ++i) {
      E2[i][0] = exp2f(trans[cl * Cq + 2 * i] * L2E);
      E2[i][1] = exp2f(trans[cl * Cq + 2 * i + 1] * L2E);
    }
    float E36 = exp2f(trans[cl * Cq + 36] * L2E);
    const float4* se4 = (const float4*)sxB;
    float b0v = (lane < Cq) ? endv[cl] : -3.0e38f;
    float KB = bcast(b0v, 0);
    float bz = (lane < Cq) ? exp2f((b0v - KB) * L2E) : 0.f;
    int eacc = 0;
    float wA = exp2f(semm[(len - 1) * Cq + cl] * L2E);
    float wB = exp2f(semm[(len - 2) * Cq + cl] * L2E);
    float wC = exp2f(semm[(len - 3) * Cq + cl] * L2E);
    float wD = exp2f(semm[(len - 4) * Cq + cl] * L2E);
    for (int t = len - 2; t >= m; --t) {
      float wcur = wA; wA = wB; wB = wC; wC = wD;
      float s = bz * wcur;
      sxB[lane] = s;
      int tn = (t - 3 > 0) ? t - 3 : 0;
      float raw = semm[tn * Cq + cl];
      float4 gv[10];
#pragma unroll
      for (int q = 0; q < 10; ++q) gv[q] = se4[q];
      int e0 = ((__float_as_int(gv[0].x) >> 23) & 255) - 127;
      float scale = __int_as_float((127 - e0) << 23);
      f32x2 sa = {0.f, 0.f}, sb2 = {0.f, 0.f};
#define FPK(i) { f32x2 g; \
      g[0] = ((i) & 1) ? gv[(i) >> 1].z : gv[(i) >> 1].x; \
      g[1] = ((i) & 1) ? gv[(i) >> 1].w : gv[(i) >> 1].y; \
      if ((i) & 1) sb2 = pk_fma(g, E2[i], sb2); else sa = pk_fma(g, E2[i], sa); }
      REP18(FPK)
#undef FPK
      float dot = ((sa[0] + sb2[0]) + (sa[1] + sb2[1])) + gv[9].x * E36;
      bz = dot * scale;
      eacc += e0;
      wD = exp2f(raw * L2E);
    }
    mrgB[lane] = (lane < Cq) ? LN2 * (log2f(bz) + (float)eacc) + KB : -3.0e38f;
  } else if (wid == 2) {
    // ---- viterbi forward, t = 1..m; v -> vh[t] (lane<40 guard) ----
    f32x2 T2[18];
#pragma unroll
    for (int i = 0; i < 18; ++i) {
      T2[i][0] = trans[(2 * i) * Cq + cl];
      T2[i][1] = trans[(2 * i + 1) * Cq + cl];
    }
    float T36 = trans[36 * Cq + cl];
    const float4* sv4 = (const float4*)sxC;
    float v = (lane < Cq) ? (startv[cl] + semm[cl]) : -3.0e38f;
    if (lane < 40) vh[0 * 40 + lane] = v;
    float emA = semm[1 * Cq + cl], emB = semm[2 * Cq + cl];
    float emC = semm[3 * Cq + cl], emD = semm[4 * Cq + cl];
    for (int t = 1; t <= m; ++t) {
      sxC[lane] = v;
      int tn = (t + 4 <= m) ? t + 4 : m;
      float raw = semm[tn * Cq + cl];
      float4 gv[10];
#pragma unroll
      for (int q = 0; q < 10; ++q) gv[q] = sv4[q];
      float m0 = -3.0e38f, m1 = -3.0e38f, m2 = -3.0e38f, m3 = -3.0e38f;
#define VPK(i) { f32x2 g; \
      g[0] = ((i) & 1) ? gv[(i) >> 1].z : gv[(i) >> 1].x; \
      g[1] = ((i) & 1) ? gv[(i) >> 1].w : gv[(i) >> 1].y; \
      f32x2 c = pk_add(g, T2[i]); \
      if (((i) & 3) == 0) m0 = fmaxf(fmaxf(m0, c[0]), c[1]); \
      else if (((i) & 3) == 1) m1 = fmaxf(fmaxf(m1, c[0]), c[1]); \
      else if (((i) & 3) == 2) m2 = fmaxf(fmaxf(m2, c[0]), c[1]); \
      else m3 = fmaxf(fmaxf(m3, c[0]), c[1]); }
      REP18(VPK)
#undef VPK
      float c36 = gv[9].x + T36;
      float best = fmaxf(fmaxf(fmaxf(m0, m1), fmaxf(m2, m3)), c36);
      float emc = emA; emA = emB; emB = emC; emC = emD;
      v = (lane < Cq) ? best + emc : -3.0e38f;
      if (lane < 40) vh[t * 40 + lane] = v;
      emD = raw;
    }
    mrgV[lane] = v;
  } else if (wid == 3) {
    // ---- viterbi backward u; vh[t+1] = u[t+1]+em[t+1] (lane<40 guard) ----
    f32x2 T2[18];
#pragma unroll
    for (int i = 0; i < 18; ++i) {
      T2[i][0] = trans[cl * Cq + 2 * i];
      T2[i][1] = trans[cl * Cq + 2 * i + 1];
    }
    float T36 = trans[cl * Cq + 36];
    const float4* sv4 = (const float4*)sxD;
    float u = (lane < Cq) ? endv[cl] : -3.0e38f;
    float emA = semm[(len - 1) * Cq + cl], emB = semm[(len - 2) * Cq + cl];
    float emC = semm[(len - 3) * Cq + cl], emD = semm[(len - 4) * Cq + cl];
    for (int t = len - 2; t >= m; --t) {
      float emc = emA; emA = emB; emB = emC; emC = emD;
      float s = u + emc;
      sxD[lane] = s;
      if (lane < 40) vh[(t + 1) * 40 + lane] = (lane < Cq) ? s : -3.0e38f;
      int tn = (t - 3 > 0) ? t - 3 : 0;
      float raw = semm[tn * Cq + cl];
      float4 gv[10];
#pragma unroll
      for (int q = 0; q < 10; ++q) gv[q] = sv4[q];
      float m0 = -3.0e38f, m1 = -3.0e38f, m2 = -3.0e38f, m3 = -3.0e38f;
#define VPK(i) { f32x2 g; \
      g[0] = ((i) & 1) ? gv[(i) >> 1].z : gv[(i) >> 1].x; \
      g[1] = ((i) & 1) ? gv[(i) >> 1].w : gv[(i) >> 1].y; \
      f32x2 c = pk_add(g, T2[i]); \
      if (((i) & 3) == 0) m0 = fmaxf(fmaxf(m0, c[0]), c[1]); \
      else if (((i) & 3) == 1) m1 = fmaxf(fmaxf(m1, c[0]), c[1]); \
      else if (((i) & 3) == 2) m2 = fmaxf(fmaxf(m2, c[0]), c[1]); \
      else m3 = fmaxf(fmaxf(m3, c[0]), c[1]); }
      REP18(VPK)
#undef VPK
      float c36 = gv[9].x + T36;
      float best = fmaxf(fmaxf(fmaxf(m0, m1), fmaxf(m2, m3)), c36);
      u = (lane < Cq) ? best : -3.0e38f;
      emD = raw;
    }
    mrgU[lane] = u;
  } else {
    // ---- gold path score ----
    const int* lab = labels + (size_t)b * Sq;
    float sc = 0.f;
#pragma unroll
    for (int k = 0; k < 8; ++k) {
      int t = 1 + lane + k * 64;
      if (t < len) {
        int lp = lab[t - 1], lt = lab[t];
        sc += trans[lp * Cq + lt] + semm[t * Cq + lt];
      }
    }
#pragma unroll
    for (int off = 32; off; off >>= 1) sc += __shfl_xor(sc, off);
    if (lane == 0) {
      int l0 = lab[0], lf = lab[len - 1];
      s_score = sc + startv[l0] + semm[l0] + endv[lf];
    }
  }
  __syncthreads();

  // ======== phase 2: merge (wave0); bp waves 1-2; fp waves 3-4 -> GLOBAL ========
  if (wid == 0) {
    float xv = (lane < Cq) ? mrgA[lane] + mrgB[lane] : -3.0e38f;
    float mm = xv;
#pragma unroll
    for (int off = 32; off; off >>= 1) mm = fmaxf(mm, __shfl_xor(mm, off));
    float es = exp2f((xv - mm) * L2E);
#pragma unroll
    for (int off = 32; off; off >>= 1) es += __shfl_xor(es, off);
    float logZ = mm + log2f(es) * LN2;
    float pv = (lane < Cq) ? mrgV[lane] + mrgU[lane] : -3.0e38f;
    int idx = (lane < Cq) ? lane : 1000;
#pragma unroll
    for (int off = 32; off; off >>= 1) {
      float po = __shfl_xor(pv, off); int io = __shfl_xor(idx, off);
      if (po > pv || (po == pv && io < idx)) { pv = po; idx = io; }
    }
    if (lane == 0) {
      llp[b] = s_score - logZ;
      lastp[b] = idx; lenp[b] = len; midp[b] = m;
    }
  } else if (wid <= 2) {
    // bp rows t = 1..m: argmax_p(vh[t-1][p] + T[p][c]); strict '>' first-index
#define DT(i) float T##i = trans[(i) * Cq + cl];
    REP37(DT)
#undef DT
    for (int t = wid; t <= m; t += 2) {
      const float4* vr4 = (const float4*)&vh[(t - 1) * 40];
      float4 gv[10];
#pragma unroll
      for (int q = 0; q < 10; ++q) gv[q] = vr4[q];
      float best = -3.0e38f; int bi = 0;
#define BARG(i) { float cnd = BR(i) + T##i; if (cnd > best) { best = cnd; bi = (i); } }
      REP37(BARG)
#undef BARG
      if (lane < Cq) bp[((size_t)b * VST + cl) * Sq + t] = (unsigned char)bi;
    }
  } else {
    // fp rows s = m+1..len-1: argmax_n(vh[s][n] + R[c][n])
#define DR(i) float R##i = trans[cl * Cq + (i)];
    REP37(DR)
#undef DR
    for (int s = m + 1 + (wid - 3); s < len; s += 2) {
      const float4* vr4 = (const float4*)&vh[s * 40];
      float4 gv[10];
#pragma unroll
      for (int q = 0; q < 10; ++q) gv[q] = vr4[q];
      float best = -3.0e38f; int bi = 0;
#define BARG(i) { float cnd = BR(i) + R##i; if (cnd > best) { best = cnd; bi = (i); } }
      REP37(BARG)
#undef BARG
      if (lane < Cq) bp[((size_t)b * VST + cl) * Sq + s] = (unsigned char)bi;
    }
  }
}

// ---------------- Kernel 3: backtrack both directions (GLOBAL bp -> registers) ----
// R16's proven walker: global uint4 loads stay in VGPRs (unlike LDS-sourced).
__global__ __launch_bounds__(64) void crf_back_kernel(
    const unsigned char* __restrict__ bp, const int* __restrict__ lenp,
    const int* __restrict__ lastp, const int* __restrict__ midp,
    float* __restrict__ outp)
{
  int b = blockIdx.x, lane = threadIdx.x;
  int len = __builtin_amdgcn_readfirstlane(lenp[b]);
  int m = __builtin_amdgcn_readfirstlane(midp[b]);
  int cstar = __builtin_amdgcn_readfirstlane(lastp[b]);
  int row = lane < VST ? lane : VST - 1;
  const uint4* src = (const uint4*)(bp + ((size_t)b * VST + row) * Sq);
  unsigned r[128];
#pragma unroll
  for (int k = 0; k < 32; ++k) {
    uint4 q = src[k];
    r[4 * k] = q.x; r[4 * k + 1] = q.y; r[4 * k + 2] = q.z; r[4 * k + 3] = q.w;
  }
  unsigned vt[8];
#pragma unroll
  for (int j = 0; j < 8; ++j) vt[j] = 0u;
#pragma unroll
  for (int j = 0; j < 8; ++j)
    vt[j] = (lane == (m & 63) && (m >> 6) == j) ? (unsigned)cstar : vt[j];
  { // forward walk: t = m+1..len-1 via fp rows (column t)
    int tag = cstar;
#pragma unroll
    for (int t = 1; t <= 510; ++t) {
      int word = __builtin_amdgcn_readlane((int)r[t >> 2], tag);
      int nt = (word >> ((t & 3) * 8)) & 0xff;
      bool live = (t > m) && (t < len);
      tag = live ? nt : tag;
      vt[t >> 6] = (lane == (t & 63) && live) ? (unsigned)tag : vt[t >> 6];
    }
  }
  { // backward walk: t = m-1..0 via bp rows (column t+1)
    int tag = cstar;
#pragma unroll
    for (int t = 510; t >= 0; --t) {
      int word = __builtin_amdgcn_readlane((int)r[(t + 1) >> 2], tag);
      int nt = (word >> (((t + 1) & 3) * 8)) & 0xff;
      bool live = (t + 1 <= m);
      tag = live ? nt : tag;
      vt[t >> 6] = (lane == (t & 63) && live) ? (unsigned)tag : vt[t >> 6];
    }
  }
#pragma unroll
  for (int j = 0; j < 8; ++j) {
    int t = j * 64 + lane;
    float o = (t < len) ? (float)(int)vt[j] : 36.0f;
    outp[(size_t)b * Sq + t] = o;
  }
}

// ---------------- Kernel 4: reduce ll partials ----------------
__global__ __launch_bounds__(64) void ll_reduce_kernel(
    const float* __restrict__ llp, float* __restrict__ outp)
{
  int lane = threadIdx.x;
  float s = llp[lane] + llp[lane + 64];
#pragma unroll
  for (int off = 32; off; off >>= 1) s += __shfl_xor(s, off);
  if (lane == 0) outp[0] = s;
}

extern "C" void kernel_launch(void* const* d_in, const int* in_sizes, int n_in,
                              void* d_out, int out_size, void* d_ws, size_t ws_size,
                              hipStream_t stream)
{
  const float* x      = (const float*)d_in[0];
  const float* W      = (const float*)d_in[1];
  const float* bias   = (const float*)d_in[2];
  const float* startv = (const float*)d_in[3];
  const float* endv   = (const float*)d_in[4];
  const float* trans  = (const float*)d_in[5];
  const int*   labels = (const int*)d_in[6];
  const unsigned char* maskb = (const unsigned char*)d_in[7];
  float* out = (float*)d_out;

  char* ws = (char*)d_ws;
  float* em            = (float*)(ws);                     // 9,699,328 B
  float* llp           = (float*)(ws + 9699328);           // 512 B
  int*   lenp          = (int*)(ws + 9699840);             // 512 B
  int*   lastp         = (int*)(ws + 9700352);             // 512 B
  int*   midp          = (int*)(ws + 9700864);             // 512 B
  unsigned short* Wbh  = (unsigned short*)(ws + 9701376);  // 73,728 B
  unsigned short* Wbl  = (unsigned short*)(ws + 9775104);  // 73,728 B
  unsigned char* bpbuf = (unsigned char*)(ws + 9848832);   // 2,621,440 B

  prep_kernel<<<144, 256, 0, stream>>>(W, Wbh, Wbl);
  emis_kernel<<<1024, 256, 0, stream>>>(x, Wbh, Wbl, bias, em);
  crf_mega_kernel<<<128, 320, 0, stream>>>(em, startv, endv, trans, labels, maskb,
                                           llp, bpbuf, lenp, lastp, midp);
  crf_back_kernel<<<128, 64, 0, stream>>>(bpbuf, lenp, lastp, midp, out + 1);
  ll_reduce_kernel<<<1, 64, 0, stream>>>(llp, out);
}

// Round 25
// 197.554 us; speedup vs baseline: 1.0302x; 1.0302x over previous
//
#include <hip/hip_runtime.h>

#define Bq 128
#define Sq 512
#define Cq 37
#define Dq 768
#define VST 40

typedef __attribute__((ext_vector_type(2))) float f32x2;
typedef __attribute__((ext_vector_type(4))) float f32x4;
typedef __attribute__((ext_vector_type(8))) short bf16x8;

static __device__ __forceinline__ f32x2 pk_fma(f32x2 a, f32x2 b, f32x2 c) {
  f32x2 d; asm("v_pk_fma_f32 %0, %1, %2, %3" : "=v"(d) : "v"(a), "v"(b), "v"(c));
  return d;
}
static __device__ __forceinline__ f32x2 pk_add(f32x2 a, f32x2 b) {
  f32x2 d; asm("v_pk_add_f32 %0, %1, %2" : "=v"(d) : "v"(a), "v"(b));
  return d;
}
static __device__ __forceinline__ float bcast(float v, int p) {
  return __int_as_float(__builtin_amdgcn_ds_bpermute(p << 2, __float_as_int(v)));
}

#define REP18(X) X(0)X(1)X(2)X(3)X(4)X(5)X(6)X(7)X(8)X(9)X(10)X(11)X(12)X(13) \
  X(14)X(15)X(16)X(17)
#define REP37(X) X(0)X(1)X(2)X(3)X(4)X(5)X(6)X(7)X(8)X(9)X(10)X(11)X(12)X(13) \
  X(14)X(15)X(16)X(17)X(18)X(19)X(20)X(21)X(22)X(23)X(24)X(25)X(26)X(27)X(28) \
  X(29)X(30)X(31)X(32)X(33)X(34)X(35)X(36)

#define BR(i) ((((i) & 3) == 0) ? gv[(i) >> 2].x : (((i) & 3) == 1) ? gv[(i) >> 2].y \
             : (((i) & 3) == 2) ? gv[(i) >> 2].z : gv[(i) >> 2].w)

// ---------------- Kernel 0: pre-split W into bf16 hi/lo B-fragments ----------------
__global__ __launch_bounds__(256) void prep_kernel(
    const float* __restrict__ W, unsigned short* __restrict__ Wbh,
    unsigned short* __restrict__ Wbl)
{
  int i = blockIdx.x * 256 + threadIdx.x;
  if (i >= 24 * 3 * 64 * 8) return;
  int ks = i / 1536, rem = i % 1536;
  int nt = rem / 512, rem2 = rem % 512;
  int lane = rem2 >> 3, j = rem2 & 7;
  int k = ks * 32 + (lane >> 4) * 8 + j;
  int c = nt * 16 + (lane & 15);
  float w = (c < Cq) ? W[(size_t)k * Cq + c] : 0.f;
  unsigned u = __float_as_uint(w);
  unsigned short h = (unsigned short)(u >> 16);
  float hr = __uint_as_float((unsigned)h << 16);
  float r = w - hr;
  Wbh[i] = h;
  Wbl[i] = (unsigned short)(__float_as_uint(r) >> 16);
}

// ---------------- Kernel 1: emissions via MFMA (R14, unchanged) ----------------
__global__ __launch_bounds__(256) void emis_kernel(
    const float* __restrict__ x, const unsigned short* __restrict__ Wbh,
    const unsigned short* __restrict__ Wbl, const float* __restrict__ bias,
    float* __restrict__ em)
{
  int tid = threadIdx.x, lane = tid & 63;
  int wv = tid >> 6;
  int tokBase = blockIdx.x * 64 + wv * 16;
  int row = lane & 15, kg = lane >> 4;
  const float* xr = x + (size_t)(tokBase + row) * Dq + kg * 8;
  const bf16x8* Bh = (const bf16x8*)Wbh;
  const bf16x8* Bl = (const bf16x8*)Wbl;
  f32x4 acc0 = {0.f, 0.f, 0.f, 0.f};
  f32x4 acc1 = {0.f, 0.f, 0.f, 0.f};
  f32x4 acc2 = {0.f, 0.f, 0.f, 0.f};

  float4 c0 = *(const float4*)(xr);
  float4 c1 = *(const float4*)(xr + 4);
  for (int ks = 0; ks < 24; ++ks) {
    float4 n0, n1;
    if (ks < 23) {
      n0 = *(const float4*)(xr + (ks + 1) * 32);
      n1 = *(const float4*)(xr + (ks + 1) * 32 + 4);
    }
    bf16x8 ah, al;
#define SPLIT(J, V) { unsigned u = __float_as_uint(V); \
    unsigned short h = (unsigned short)(u >> 16); \
    float hr = __uint_as_float((unsigned)h << 16); \
    float rr = (V) - hr; \
    ah[J] = (short)h; al[J] = (short)(__float_as_uint(rr) >> 16); }
    SPLIT(0, c0.x) SPLIT(1, c0.y) SPLIT(2, c0.z) SPLIT(3, c0.w)
    SPLIT(4, c1.x) SPLIT(5, c1.y) SPLIT(6, c1.z) SPLIT(7, c1.w)
#undef SPLIT
    int fi = (ks * 3) * 64 + lane;
    bf16x8 bh0 = Bh[fi], bh1 = Bh[fi + 64], bh2 = Bh[fi + 128];
    bf16x8 bl0 = Bl[fi], bl1 = Bl[fi + 64], bl2 = Bl[fi + 128];
    acc0 = __builtin_amdgcn_mfma_f32_16x16x32_bf16(al, bh0, acc0, 0, 0, 0);
    acc1 = __builtin_amdgcn_mfma_f32_16x16x32_bf16(al, bh1, acc1, 0, 0, 0);
    acc2 = __builtin_amdgcn_mfma_f32_16x16x32_bf16(al, bh2, acc2, 0, 0, 0);
    acc0 = __builtin_amdgcn_mfma_f32_16x16x32_bf16(ah, bl0, acc0, 0, 0, 0);
    acc1 = __builtin_amdgcn_mfma_f32_16x16x32_bf16(ah, bl1, acc1, 0, 0, 0);
    acc2 = __builtin_amdgcn_mfma_f32_16x16x32_bf16(ah, bl2, acc2, 0, 0, 0);
    acc0 = __builtin_amdgcn_mfma_f32_16x16x32_bf16(ah, bh0, acc0, 0, 0, 0);
    acc1 = __builtin_amdgcn_mfma_f32_16x16x32_bf16(ah, bh1, acc1, 0, 0, 0);
    acc2 = __builtin_amdgcn_mfma_f32_16x16x32_bf16(ah, bh2, acc2, 0, 0, 0);
    c0 = n0; c1 = n1;
  }
  int colc = lane & 15;
#pragma unroll
  for (int r = 0; r < 4; ++r) {
    size_t tok = (size_t)tokBase + kg * 4 + r;
    em[tok * Cq + colc]      = acc0[r] + bias[colc];
    em[tok * Cq + 16 + colc] = acc1[r] + bias[16 + colc];
    if (colc < 5)
      em[tok * Cq + 32 + colc] = acc2[r] + bias[32 + colc];
  }
}

// ---------------- Kernel 2: MEGA CRF (phases 1-2; bp bytes -> GLOBAL; R24) ----------
__global__ __launch_bounds__(320) void crf_mega_kernel(
    const float* __restrict__ em, const float* __restrict__ startv,
    const float* __restrict__ endv, const float* __restrict__ trans,
    const int* __restrict__ labels, const unsigned char* __restrict__ maskb,
    float* __restrict__ llp, unsigned char* __restrict__ bp,
    int* __restrict__ lenp, int* __restrict__ lastp, int* __restrict__ midp)
{
  __shared__ float semm[(Sq + 4) * Cq];
  __shared__ float vh[Sq * 40];
  __shared__ __align__(16) float sxA[64];
  __shared__ __align__(16) float sxB[64];
  __shared__ __align__(16) float sxC[64];
  __shared__ __align__(16) float sxD[64];
  __shared__ float mrgA[64], mrgB[64], mrgV[64], mrgU[64];
  __shared__ float s_score;
  int b = blockIdx.x;
  int tid = threadIdx.x, wid = tid >> 6, lane = tid & 63;
  int cl = lane < Cq ? lane : Cq - 1;

  int esz4 = (maskb[1] == 0) ? 1 : 0;
  int len = 0;
#pragma unroll
  for (int k = 0; k < 8; ++k) {
    size_t t = (size_t)lane + (size_t)k * 64;
    unsigned char mb = esz4 ? maskb[((size_t)b * Sq + t) * 4] : maskb[(size_t)b * Sq + t];
    len += (mb != 0);
  }
#pragma unroll
  for (int off = 32; off; off >>= 1) len += __shfl_xor(len, off);
  int m = len >> 1;

  const float4* src4 = (const float4*)(em + (size_t)b * Sq * Cq);
  float4* dst4 = (float4*)semm;
  for (int i = tid; i < (Sq * Cq) / 4; i += 320) dst4[i] = src4[i];
  if (tid < 4 * Cq) semm[Sq * Cq + tid] = 0.f;
  __syncthreads();

  const float L2E = 1.4426950408889634f, LN2 = 0.6931471805599453f;

  if (wid == 0) {
    // ---- alpha forward, exp domain, t = 1..m ----
    f32x2 E2[18];
#pragma unroll
    for (int i = 0; i < 18; ++i) {
      E2[i][0] = exp2f(trans[(2 * i) * Cq + cl] * L2E);
      E2[i][1] = exp2f(trans[(2 * i + 1) * Cq + cl] * L2E);
    }
    float E36 = exp2f(trans[36 * Cq + cl] * L2E);
    const float4* se4 = (const float4*)sxA;
    float a0 = (lane < Cq) ? (startv[cl] + semm[cl]) : -3.0e38f;
    float K0 = bcast(a0, 0);
    float ez = (lane < Cq) ? exp2f((a0 - K0) * L2E) : 0.f;
    int eacc = 0;
    float wA = exp2f(semm[1 * Cq + cl] * L2E), wB = exp2f(semm[2 * Cq + cl] * L2E);
    float wC = exp2f(semm[3 * Cq + cl] * L2E), wD = exp2f(semm[4 * Cq + cl] * L2E);
    for (int t = 1; t <= m; ++t) {
      sxA[lane] = ez;
      int tn = (t + 4 <= m) ? t + 4 : m;
      float raw = semm[tn * Cq + cl];
      float4 gv[10];
#pragma unroll
      for (int q = 0; q < 10; ++q) gv[q] = se4[q];
      int e0 = ((__float_as_int(gv[0].x) >> 23) & 255) - 127;
      float scale = __int_as_float((127 - e0) << 23);
      f32x2 sa = {0.f, 0.f}, sb2 = {0.f, 0.f};
#define FPK(i) { f32x2 g; \
      g[0] = ((i) & 1) ? gv[(i) >> 1].z : gv[(i) >> 1].x; \
      g[1] = ((i) & 1) ? gv[(i) >> 1].w : gv[(i) >> 1].y; \
      if ((i) & 1) sb2 = pk_fma(g, E2[i], sb2); else sa = pk_fma(g, E2[i], sa); }
      REP18(FPK)
#undef FPK
      float dot = ((sa[0] + sb2[0]) + (sa[1] + sb2[1])) + gv[9].x * E36;
      float wcur = wA; wA = wB; wB = wC; wC = wD;
      ez = dot * (wcur * scale);
      eacc += e0;
      wD = exp2f(raw * L2E);
    }
    mrgA[lane] = (lane < Cq) ? LN2 * (log2f(ez) + (float)eacc) + K0 : -3.0e38f;
  } else if (wid == 1) {
    // ---- beta backward, exp domain, t = len-2..m (row-dot) ----
    f32x2 E2[18];
#pragma unroll
    for (int i = 0; i < 18; ++i) {
      E2[i][0] = exp2f(trans[cl * Cq + 2 * i] * L2E);
      E2[i][1] = exp2f(trans[cl * Cq + 2 * i + 1] * L2E);
    }
    float E36 = exp2f(trans[cl * Cq + 36] * L2E);
    const float4* se4 = (const float4*)sxB;
    float b0v = (lane < Cq) ? endv[cl] : -3.0e38f;
    float KB = bcast(b0v, 0);
    float bz = (lane < Cq) ? exp2f((b0v - KB) * L2E) : 0.f;
    int eacc = 0;
    float wA = exp2f(semm[(len - 1) * Cq + cl] * L2E);
    float wB = exp2f(semm[(len - 2) * Cq + cl] * L2E);
    float wC = exp2f(semm[(len - 3) * Cq + cl] * L2E);
    float wD = exp2f(semm[(len - 4) * Cq + cl] * L2E);
    for (int t = len - 2; t >= m; --t) {
      float wcur = wA; wA = wB; wB = wC; wC = wD;
      float s = bz * wcur;
      sxB[lane] = s;
      int tn = (t - 3 > 0) ? t - 3 : 0;
      float raw = semm[tn * Cq + cl];
      float4 gv[10];
#pragma unroll
      for (int q = 0; q < 10; ++q) gv[q] = se4[q];
      int e0 = ((__float_as_int(gv[0].x) >> 23) & 255) - 127;
      float scale = __int_as_float((127 - e0) << 23);
      f32x2 sa = {0.f, 0.f}, sb2 = {0.f, 0.f};
#define FPK(i) { f32x2 g; \
      g[0] = ((i) & 1) ? gv[(i) >> 1].z : gv[(i) >> 1].x; \
      g[1] = ((i) & 1) ? gv[(i) >> 1].w : gv[(i) >> 1].y; \
      if ((i) & 1) sb2 = pk_fma(g, E2[i], sb2); else sa = pk_fma(g, E2[i], sa); }
      REP18(FPK)
#undef FPK
      float dot = ((sa[0] + sb2[0]) + (sa[1] + sb2[1])) + gv[9].x * E36;
      bz = dot * scale;
      eacc += e0;
      wD = exp2f(raw * L2E);
    }
    mrgB[lane] = (lane < Cq) ? LN2 * (log2f(bz) + (float)eacc) + KB : -3.0e38f;
  } else if (wid == 2) {
    // ---- viterbi forward, t = 1..m; v -> vh[t] (lane<40 guard) ----
    f32x2 T2[18];
#pragma unroll
    for (int i = 0; i < 18; ++i) {
      T2[i][0] = trans[(2 * i) * Cq + cl];
      T2[i][1] = trans[(2 * i + 1) * Cq + cl];
    }
    float T36 = trans[36 * Cq + cl];
    const float4* sv4 = (const float4*)sxC;
    float v = (lane < Cq) ? (startv[cl] + semm[cl]) : -3.0e38f;
    if (lane < 40) vh[0 * 40 + lane] = v;
    float emA = semm[1 * Cq + cl], emB = semm[2 * Cq + cl];
    float emC = semm[3 * Cq + cl], emD = semm[4 * Cq + cl];
    for (int t = 1; t <= m; ++t) {
      sxC[lane] = v;
      int tn = (t + 4 <= m) ? t + 4 : m;
      float raw = semm[tn * Cq + cl];
      float4 gv[10];
#pragma unroll
      for (int q = 0; q < 10; ++q) gv[q] = sv4[q];
      float m0 = -3.0e38f, m1 = -3.0e38f, m2 = -3.0e38f, m3 = -3.0e38f;
#define VPK(i) { f32x2 g; \
      g[0] = ((i) & 1) ? gv[(i) >> 1].z : gv[(i) >> 1].x; \
      g[1] = ((i) & 1) ? gv[(i) >> 1].w : gv[(i) >> 1].y; \
      f32x2 c = pk_add(g, T2[i]); \
      if (((i) & 3) == 0) m0 = fmaxf(fmaxf(m0, c[0]), c[1]); \
      else if (((i) & 3) == 1) m1 = fmaxf(fmaxf(m1, c[0]), c[1]); \
      else if (((i) & 3) == 2) m2 = fmaxf(fmaxf(m2, c[0]), c[1]); \
      else m3 = fmaxf(fmaxf(m3, c[0]), c[1]); }
      REP18(VPK)
#undef VPK
      float c36 = gv[9].x + T36;
      float best = fmaxf(fmaxf(fmaxf(m0, m1), fmaxf(m2, m3)), c36);
      float emc = emA; emA = emB; emB = emC; emC = emD;
      v = (lane < Cq) ? best + emc : -3.0e38f;
      if (lane < 40) vh[t * 40 + lane] = v;
      emD = raw;
    }
    mrgV[lane] = v;
  } else if (wid == 3) {
    // ---- viterbi backward u; vh[t+1] = u[t+1]+em[t+1] (lane<40 guard) ----
    f32x2 T2[18];
#pragma unroll
    for (int i = 0; i < 18; ++i) {
      T2[i][0] = trans[cl * Cq + 2 * i];
      T2[i][1] = trans[cl * Cq + 2 * i + 1];
    }
    float T36 = trans[cl * Cq + 36];
    const float4* sv4 = (const float4*)sxD;
    float u = (lane < Cq) ? endv[cl] : -3.0e38f;
    float emA = semm[(len - 1) * Cq + cl], emB = semm[(len - 2) * Cq + cl];
    float emC = semm[(len - 3) * Cq + cl], emD = semm[(len - 4) * Cq + cl];
    for (int t = len - 2; t >= m; --t) {
      float emc = emA; emA = emB; emB = emC; emC = emD;
      float s = u + emc;
      sxD[lane] = s;
      if (lane < 40) vh[(t + 1) * 40 + lane] = (lane < Cq) ? s : -3.0e38f;
      int tn = (t - 3 > 0) ? t - 3 : 0;
      float raw = semm[tn * Cq + cl];
      float4 gv[10];
#pragma unroll
      for (int q = 0; q < 10; ++q) gv[q] = sv4[q];
      float m0 = -3.0e38f, m1 = -3.0e38f, m2 = -3.0e38f, m3 = -3.0e38f;
#define VPK(i) { f32x2 g; \
      g[0] = ((i) & 1) ? gv[(i) >> 1].z : gv[(i) >> 1].x; \
      g[1] = ((i) & 1) ? gv[(i) >> 1].w : gv[(i) >> 1].y; \
      f32x2 c = pk_add(g, T2[i]); \
      if (((i) & 3) == 0) m0 = fmaxf(fmaxf(m0, c[0]), c[1]); \
      else if (((i) & 3) == 1) m1 = fmaxf(fmaxf(m1, c[0]), c[1]); \
      else if (((i) & 3) == 2) m2 = fmaxf(fmaxf(m2, c[0]), c[1]); \
      else m3 = fmaxf(fmaxf(m3, c[0]), c[1]); }
      REP18(VPK)
#undef VPK
      float c36 = gv[9].x + T36;
      float best = fmaxf(fmaxf(fmaxf(m0, m1), fmaxf(m2, m3)), c36);
      u = (lane < Cq) ? best : -3.0e38f;
      emD = raw;
    }
    mrgU[lane] = u;
  } else {
    // ---- gold path score ----
    const int* lab = labels + (size_t)b * Sq;
    float sc = 0.f;
#pragma unroll
    for (int k = 0; k < 8; ++k) {
      int t = 1 + lane + k * 64;
      if (t < len) {
        int lp = lab[t - 1], lt = lab[t];
        sc += trans[lp * Cq + lt] + semm[t * Cq + lt];
      }
    }
#pragma unroll
    for (int off = 32; off; off >>= 1) sc += __shfl_xor(sc, off);
    if (lane == 0) {
      int l0 = lab[0], lf = lab[len - 1];
      s_score = sc + startv[l0] + semm[l0] + endv[lf];
    }
  }
  __syncthreads();

  // ======== phase 2: merge (wave0); bp waves 1-2; fp waves 3-4 -> GLOBAL ========
  if (wid == 0) {
    float xv = (lane < Cq) ? mrgA[lane] + mrgB[lane] : -3.0e38f;
    float mm = xv;
#pragma unroll
    for (int off = 32; off; off >>= 1) mm = fmaxf(mm, __shfl_xor(mm, off));
    float es = exp2f((xv - mm) * L2E);
#pragma unroll
    for (int off = 32; off; off >>= 1) es += __shfl_xor(es, off);
    float logZ = mm + log2f(es) * LN2;
    float pv = (lane < Cq) ? mrgV[lane] + mrgU[lane] : -3.0e38f;
    int idx = (lane < Cq) ? lane : 1000;
#pragma unroll
    for (int off = 32; off; off >>= 1) {
      float po = __shfl_xor(pv, off); int io = __shfl_xor(idx, off);
      if (po > pv || (po == pv && io < idx)) { pv = po; idx = io; }
    }
    if (lane == 0) {
      llp[b] = s_score - logZ;
      lastp[b] = idx; lenp[b] = len; midp[b] = m;
    }
  } else if (wid <= 2) {
    // bp rows t = 1..m: argmax_p(vh[t-1][p] + T[p][c]); strict '>' first-index
#define DT(i) float T##i = trans[(i) * Cq + cl];
    REP37(DT)
#undef DT
    for (int t = wid; t <= m; t += 2) {
      const float4* vr4 = (const float4*)&vh[(t - 1) * 40];
      float4 gv[10];
#pragma unroll
      for (int q = 0; q < 10; ++q) gv[q] = vr4[q];
      float best = -3.0e38f; int bi = 0;
#define BARG(i) { float cnd = BR(i) + T##i; if (cnd > best) { best = cnd; bi = (i); } }
      REP37(BARG)
#undef BARG
      if (lane < Cq) bp[((size_t)b * VST + cl) * Sq + t] = (unsigned char)bi;
    }
  } else {
    // fp rows s = m+1..len-1: argmax_n(vh[s][n] + R[c][n])
#define DR(i) float R##i = trans[cl * Cq + (i)];
    REP37(DR)
#undef DR
    for (int s = m + 1 + (wid - 3); s < len; s += 2) {
      const float4* vr4 = (const float4*)&vh[s * 40];
      float4 gv[10];
#pragma unroll
      for (int q = 0; q < 10; ++q) gv[q] = vr4[q];
      float best = -3.0e38f; int bi = 0;
#define BARG(i) { float cnd = BR(i) + R##i; if (cnd > best) { best = cnd; bi = (i); } }
      REP37(BARG)
#undef BARG
      if (lane < Cq) bp[((size_t)b * VST + cl) * Sq + s] = (unsigned char)bi;
    }
  }
}

// ---------------- Kernel 3: split backtrack walks + fused ll-reduce ----------------
// wid0: backward walk (t<=m). wid1: forward walk (t>m). wid2 (block 0 only):
// reduce llp -> out[0]. Global-sourced r[128] stays in VGPRs.
__global__ __launch_bounds__(192) void crf_back_kernel(
    const unsigned char* __restrict__ bp, const int* __restrict__ lenp,
    const int* __restrict__ lastp, const int* __restrict__ midp,
    const float* __restrict__ llp, float* __restrict__ outp,
    float* __restrict__ llout)
{
  int b = blockIdx.x, tid = threadIdx.x, wid = tid >> 6, lane = tid & 63;
  if (wid == 2) {
    if (b == 0) {
      float s = llp[lane] + llp[lane + 64];
#pragma unroll
      for (int off = 32; off; off >>= 1) s += __shfl_xor(s, off);
      if (lane == 0) llout[0] = s;
    }
    return;
  }
  int len = __builtin_amdgcn_readfirstlane(lenp[b]);
  int m = __builtin_amdgcn_readfirstlane(midp[b]);
  int cstar = __builtin_amdgcn_readfirstlane(lastp[b]);
  int row = lane < VST ? lane : VST - 1;
  const uint4* src = (const uint4*)(bp + ((size_t)b * VST + row) * Sq);
  unsigned r[128];
#pragma unroll
  for (int k = 0; k < 32; ++k) {
    uint4 q = src[k];
    r[4 * k] = q.x; r[4 * k + 1] = q.y; r[4 * k + 2] = q.z; r[4 * k + 3] = q.w;
  }
  unsigned vt[8];
#pragma unroll
  for (int j = 0; j < 8; ++j) vt[j] = 0u;
  if (wid == 0) {
    // backward walk: tags 0..m (seed at m), via bp rows (column t+1)
#pragma unroll
    for (int j = 0; j < 8; ++j)
      vt[j] = (lane == (m & 63) && (m >> 6) == j) ? (unsigned)cstar : vt[j];
    int tag = cstar;
#pragma unroll
    for (int t = 510; t >= 0; --t) {
      int word = __builtin_amdgcn_readlane((int)r[(t + 1) >> 2], tag);
      int nt = (word >> (((t + 1) & 3) * 8)) & 0xff;
      bool live = (t + 1 <= m);
      tag = live ? nt : tag;
      vt[t >> 6] = (lane == (t & 63) && live) ? (unsigned)tag : vt[t >> 6];
    }
#pragma unroll
    for (int j = 0; j < 8; ++j) {
      int t = j * 64 + lane;
      if (t <= m) outp[(size_t)b * Sq + t] = (float)(int)vt[j];
    }
  } else {
    // forward walk: tags m+1..len-1 via fp rows (column t); pads to 511
    int tag = cstar;
#pragma unroll
    for (int t = 1; t <= 510; ++t) {
      int word = __builtin_amdgcn_readlane((int)r[t >> 2], tag);
      int nt = (word >> ((t & 3) * 8)) & 0xff;
      bool live = (t > m) && (t < len);
      tag = live ? nt : tag;
      vt[t >> 6] = (lane == (t & 63) && live) ? (unsigned)tag : vt[t >> 6];
    }
#pragma unroll
    for (int j = 0; j < 8; ++j) {
      int t = j * 64 + lane;
      if (t > m) {
        float o = (t < len) ? (float)(int)vt[j] : 36.0f;
        outp[(size_t)b * Sq + t] = o;
      }
    }
  }
}

extern "C" void kernel_launch(void* const* d_in, const int* in_sizes, int n_in,
                              void* d_out, int out_size, void* d_ws, size_t ws_size,
                              hipStream_t stream)
{
  const float* x      = (const float*)d_in[0];
  const float* W      = (const float*)d_in[1];
  const float* bias   = (const float*)d_in[2];
  const float* startv = (const float*)d_in[3];
  const float* endv   = (const float*)d_in[4];
  const float* trans  = (const float*)d_in[5];
  const int*   labels = (const int*)d_in[6];
  const unsigned char* maskb = (const unsigned char*)d_in[7];
  float* out = (float*)d_out;

  char* ws = (char*)d_ws;
  float* em            = (float*)(ws);                     // 9,699,328 B
  float* llp           = (float*)(ws + 9699328);           // 512 B
  int*   lenp          = (int*)(ws + 9699840);             // 512 B
  int*   lastp         = (int*)(ws + 9700352);             // 512 B
  int*   midp          = (int*)(ws + 9700864);             // 512 B
  unsigned short* Wbh  = (unsigned short*)(ws + 9701376);  // 73,728 B
  unsigned short* Wbl  = (unsigned short*)(ws + 9775104);  // 73,728 B
  unsigned char* bpbuf = (unsigned char*)(ws + 9848832);   // 2,621,440 B

  prep_kernel<<<144, 256, 0, stream>>>(W, Wbh, Wbl);
  emis_kernel<<<1024, 256, 0, stream>>>(x, Wbh, Wbl, bias, em);
  crf_mega_kernel<<<128, 320, 0, stream>>>(em, startv, endv, trans, labels, maskb,
                                           llp, bpbuf, lenp, lastp, midp);
  crf_back_kernel<<<128, 192, 0, stream>>>(bpbuf, lenp, lastp, midp, llp,
                                           out + 1, out);
}